// Round 2
// baseline (1917.060 us; speedup 1.0000x reference)
//
#include <hip/hip_runtime.h>

#define K_DIM 128

// ---- path tables: PATHS order = l1-major, then l2, then l3 (ascending) ----
__device__ const int d_l1[34] = {0,0,0,0, 1,1,1,1,1,1,1,1,1, 2,2,2,2,2,2,2,2,2,2,2, 3,3,3,3,3,3,3,3,3,3};
__device__ const int d_l2[34] = {0,1,2,3, 0,1,1,1,2,2,2,3,3, 0,1,1,1,2,2,2,2,3,3,3, 0,1,1,2,2,2,3,3,3,3};
__device__ const int d_l3[34] = {0,1,2,3, 1,0,1,2,1,2,3,2,3, 2,1,2,3,0,1,2,3,1,2,3, 3,2,3,1,2,3,0,1,2,3};
// per-l3 path lists (global path indices, ascending = concat order), counts {4,9,11,10}
__device__ const int d_pl3[4][11] = {
  {0,5,17,30, 0,0,0,0,0,0,0},
  {1,4,6,8,14,18,21,27,31, 0,0},
  {2,7,9,11,13,15,19,22,25,28,32},
  {3,10,12,16,20,23,24,26,29,33, 0}
};
__device__ const int d_np[4] = {4,9,11,10};

__device__ double dfactd(int n){ double r=1.0; for(int i=2;i<=n;++i) r*=(double)i; return r; }

// C2[p][m1i][m2i] = CG(l1,m1,l2,m2,l3,m1+m2), 34*49 floats into d_ws
__global__ void cg_init(float* __restrict__ C2) {
    int e = blockIdx.x*blockDim.x + threadIdx.x;
    if (e >= 34*49) return;
    int p = e/49, r = e%49, m1i = r/7, m2i = r%7;
    int l1 = d_l1[p], l2 = d_l2[p], l3 = d_l3[p];
    float val = 0.f;
    if (m1i < 2*l1+1 && m2i < 2*l2+1) {
        int m1 = m1i-l1, m2 = m2i-l2, m3 = m1+m2;
        if (m3 >= -l3 && m3 <= l3) {
            double pref = sqrt((double)(2*l3+1) * dfactd(l3+l1-l2)*dfactd(l3-l1+l2)
                               * dfactd(l1+l2-l3) / dfactd(l1+l2+l3+1));
            pref *= sqrt(dfactd(l3+m3)*dfactd(l3-m3)*dfactd(l1-m1)*dfactd(l1+m1)
                         *dfactd(l2-m2)*dfactd(l2+m2));
            int kmin = max(0, max(l2-l3-m1, l1-l3+m2));
            int kmax = min(l1+l2-l3, min(l1-m1, l2+m2));
            double s = 0.0;
            for (int k=kmin;k<=kmax;++k) {
                double t = dfactd(k)*dfactd(l1+l2-l3-k)*dfactd(l1-m1-k)
                         * dfactd(l2+m2-k)*dfactd(l3-l2+m1+k)*dfactd(l3-l1-m2+k);
                s += ((k&1)? -1.0:1.0)/t;
            }
            val = (float)(pref*s);
        }
    }
    C2[e] = val;
}

// Fused TP + mix GEMM + residual. One block = 128 rows of l3's GEMM
// (row = n*(2l3+1)+m3i), full 128 output cols. Inner dim chunked per path
// (128 ch) in two 64-halves: TP tile -> LDS, W chunk -> LDS, 8x8 reg tile.
__global__ __launch_bounds__(256) void cg_main(
    const float* __restrict__ f10, const float* __restrict__ f11,
    const float* __restrict__ f12, const float* __restrict__ f13,
    const float* __restrict__ f20, const float* __restrict__ f21,
    const float* __restrict__ f22, const float* __restrict__ f23,
    const float* __restrict__ W0, const float* __restrict__ W1,
    const float* __restrict__ W2, const float* __restrict__ W3,
    const float* __restrict__ C2, float* __restrict__ out)
{
    __shared__ float As[128][65];    // [row][k'] +1 pad
    __shared__ float Ws[64][128];    // [k'][outcol]
    __shared__ float C2s[49];
    __shared__ int rowN[128];
    __shared__ int rowM[128];

    const float* f1s[4] = {f10,f11,f12,f13};
    const float* f2s[4] = {f20,f21,f22,f23};
    const float* Wls[4] = {W0,W1,W2,W3};

    int b = blockIdx.x;
    int l3, rb;
    if (b < 64)       { l3=0; rb=b; }
    else if (b < 256) { l3=1; rb=b-64; }
    else if (b < 576) { l3=2; rb=b-256; }
    else              { l3=3; rb=b-576; }
    const int TL3 = 2*l3+1;
    const int row0 = rb*128;
    const int tid  = threadIdx.x;
    const size_t obase = (size_t)1048576 * (size_t)((l3==0)?0:(l3==1)?1:(l3==2)?4:9);

    if (tid < 128) {
        int rg = row0 + tid;
        rowN[tid] = rg / TL3;
        rowM[tid] = rg % TL3;
    }

    float acc[8][8];
    for (int j=0;j<8;++j)
        for (int q=0;q<8;++q)
            acc[j][q]=0.f;

    const int tx = tid & 63;   // TP: k' lane
    const int ty = tid >> 6;   // TP: row phase 0..3
    const int rr = tid >> 4;   // GEMM rows rr+16j (conflict-free interleave)
    const int cc = tid & 15;   // GEMM cols cc+16q

    const int np = d_np[l3];
    const float* __restrict__ Wl = Wls[l3];

    for (int pi=0; pi<np; ++pi) {
        int p  = d_pl3[l3][pi];
        int l1 = d_l1[p], l2 = d_l2[p];
        const float* __restrict__ F1 = f1s[l1];
        const float* __restrict__ F2 = f2s[l2];
        const int d1 = 2*l1+1, d2 = 2*l2+1;
        if (tid < 49) C2s[tid] = C2[p*49 + tid];

        for (int h=0; h<2; ++h) {
            __syncthreads();   // prev GEMM done; C2s/rowN visible after this
            // --- stage W chunk: rows pi*128+h*64 .. +63, all 128 cols ---
            {
                const float4* src = reinterpret_cast<const float4*>(
                    Wl + (size_t)(pi*128 + h*64) * K_DIM);
                #pragma unroll
                for (int q=0;q<8;++q) {
                    int f = tid + q*256;      // 2048 float4s total
                    int r = f >> 5, c4 = f & 31;
                    float4 v = src[(size_t)r*32 + c4];
                    *reinterpret_cast<float4*>(&Ws[r][c4*4]) = v;
                }
            }
            // --- TP tile: As[r][tx] for r=ty+4j ---
            #pragma unroll 2
            for (int j=0;j<32;++j) {
                int r = ty + 4*j;
                int n = rowN[r];
                int m3 = rowM[r] - l3;
                float a = 0.f;
                for (int m1i=0; m1i<d1; ++m1i) {
                    int m2i = m3 - (m1i - l1) + l2;
                    if (m2i >= 0 && m2i < d2) {
                        float c = C2s[m1i*7+m2i];
                        if (c != 0.f) {
                            float v1 = F1[((size_t)n*d1+m1i)*K_DIM + h*64 + tx];
                            float v2 = F2[((size_t)n*d2+m2i)*K_DIM + h*64 + tx];
                            a = fmaf(c*v1, v2, a);
                        }
                    }
                }
                As[r][tx] = a;
            }
            __syncthreads();
            // --- GEMM accumulate over 64 inner ---
            #pragma unroll 2
            for (int i=0;i<64;++i) {
                float av[8], wv[8];
                #pragma unroll
                for (int j=0;j<8;++j) av[j] = As[rr + 16*j][i];
                #pragma unroll
                for (int q=0;q<8;++q) wv[q] = Ws[i][cc + 16*q];
                #pragma unroll
                for (int j=0;j<8;++j)
                    #pragma unroll
                    for (int q=0;q<8;++q)
                        acc[j][q] = fmaf(av[j], wv[q], acc[j][q]);
            }
        }
    }

    // --- epilogue: residual + store ---
    const float* __restrict__ F1r = f1s[l3];
    #pragma unroll
    for (int j=0;j<8;++j) {
        int r = rr + 16*j;
        size_t rowoff = (size_t)(row0 + r) * K_DIM;
        #pragma unroll
        for (int q=0;q<8;++q) {
            int c = cc + 16*q;
            out[obase + rowoff + c] = F1r[rowoff + c] + acc[j][q];
        }
    }
}

extern "C" void kernel_launch(void* const* d_in, const int* in_sizes, int n_in,
                              void* d_out, int out_size, void* d_ws, size_t ws_size,
                              hipStream_t stream) {
    // setup_inputs dict order is INTERLEAVED: f1_l, f2_l, W_l per l
    const float* f10 = (const float*)d_in[0];
    const float* f20 = (const float*)d_in[1];
    const float* W0  = (const float*)d_in[2];
    const float* f11 = (const float*)d_in[3];
    const float* f21 = (const float*)d_in[4];
    const float* W1  = (const float*)d_in[5];
    const float* f12 = (const float*)d_in[6];
    const float* f22 = (const float*)d_in[7];
    const float* W2  = (const float*)d_in[8];
    const float* f13 = (const float*)d_in[9];
    const float* f23 = (const float*)d_in[10];
    const float* W3  = (const float*)d_in[11];
    float* C2  = (float*)d_ws;           // 34*49 floats
    float* out = (float*)d_out;

    hipLaunchKernelGGL(cg_init, dim3(7), dim3(256), 0, stream, C2);
    hipLaunchKernelGGL(cg_main, dim3(1024), dim3(256), 0, stream,
        f10,f11,f12,f13, f20,f21,f22,f23, W0,W1,W2,W3, C2, out);
}

// Round 3
// 1071.125 us; speedup vs baseline: 1.7898x; 1.7898x over previous
//
#include <hip/hip_runtime.h>

#define K_DIM 128

typedef __attribute__((ext_vector_type(8))) short short8;
typedef __attribute__((ext_vector_type(4))) float f32x4;

// ---- path tables: PATHS order = l1-major, then l2, then l3 (ascending) ----
__device__ const int d_l1[34] = {0,0,0,0, 1,1,1,1,1,1,1,1,1, 2,2,2,2,2,2,2,2,2,2,2, 3,3,3,3,3,3,3,3,3,3};
__device__ const int d_l2[34] = {0,1,2,3, 0,1,1,1,2,2,2,3,3, 0,1,1,1,2,2,2,2,3,3,3, 0,1,1,2,2,2,3,3,3,3};
__device__ const int d_l3v[34]= {0,1,2,3, 1,0,1,2,1,2,3,2,3, 2,1,2,3,0,1,2,3,1,2,3, 3,2,3,1,2,3,0,1,2,3};
// per-l3 path lists (global path indices ascending = concat order), counts {4,9,11,10}
__device__ const int d_pl3[4][11] = {
  {0,5,17,30, 0,0,0,0,0,0,0},
  {1,4,6,8,14,18,21,27,31, 0,0},
  {2,7,9,11,13,15,19,22,25,28,32},
  {3,10,12,16,20,23,24,26,29,33, 0}
};
__device__ const int d_np[4]   = {4,9,11,10};
__device__ const int d_csum[4] = {0,8,26,48};   // chunk-id base per l3 (chunk = 64-ch half-path)

__device__ double dfactd(int n){ double r=1.0; for(int i=2;i<=n;++i) r*=(double)i; return r; }

__device__ __forceinline__ unsigned short f2bf(float x) {
    unsigned int b = __float_as_uint(x);
    return (unsigned short)((b + 0x7FFFu + ((b >> 16) & 1u)) >> 16);
}

// C2[p][m1i][m2i] = CG(l1,m1,l2,m2,l3,m1+m2), 34*49 floats at d_ws+0
__global__ void cg_init(float* __restrict__ C2) {
    int e = blockIdx.x*blockDim.x + threadIdx.x;
    if (e >= 34*49) return;
    int p = e/49, r = e%49, m1i = r/7, m2i = r%7;
    int l1 = d_l1[p], l2 = d_l2[p], l3 = d_l3v[p];
    float val = 0.f;
    if (m1i < 2*l1+1 && m2i < 2*l2+1) {
        int m1 = m1i-l1, m2 = m2i-l2, m3 = m1+m2;
        if (m3 >= -l3 && m3 <= l3) {
            double pref = sqrt((double)(2*l3+1) * dfactd(l3+l1-l2)*dfactd(l3-l1+l2)
                               * dfactd(l1+l2-l3) / dfactd(l1+l2+l3+1));
            pref *= sqrt(dfactd(l3+m3)*dfactd(l3-m3)*dfactd(l1-m1)*dfactd(l1+m1)
                         *dfactd(l2-m2)*dfactd(l2+m2));
            int kmin = max(0, max(l2-l3-m1, l1-l3+m2));
            int kmax = min(l1+l2-l3, min(l1-m1, l2+m2));
            double s = 0.0;
            for (int k=kmin;k<=kmax;++k) {
                double t = dfactd(k)*dfactd(l1+l2-l3-k)*dfactd(l1-m1-k)
                         * dfactd(l2+m2-k)*dfactd(l3-l2+m1+k)*dfactd(l3-l1-m2+k);
                s += ((k&1)? -1.0:1.0)/t;
            }
            val = (float)(pref*s);
        }
    }
    C2[e] = val;
}

// W -> bf16, transposed to [col][kk], XOR-swizzled, tiled per 64-ch chunk.
// Tile (chunk c): ushort[128 col][64 kk] at wt + c*8192, element (col,kk) at
// idx col*64 + (kk ^ ((col&7)<<3))  (byte: col*128 + (2kk ^ ((col&7)<<4))).
// kin = local_chunk*64 + kk  where local_chunk = pi*2+h.
__global__ void wt_prep(const float* __restrict__ W0, const float* __restrict__ W1,
                        const float* __restrict__ W2, const float* __restrict__ W3,
                        unsigned short* __restrict__ wt) {
    int b = blockIdx.x;                    // 68*32 blocks
    int chunk = b >> 5;
    int e = ((b & 31) << 8) + threadIdx.x; // 0..8191 within tile
    int kk = e & 63, col = e >> 6;
    int l3 = (chunk < 8) ? 0 : (chunk < 26) ? 1 : (chunk < 48) ? 2 : 3;
    int local = chunk - d_csum[l3];
    int kin = local*64 + kk;
    const float* W = (l3==0)?W0:(l3==1)?W1:(l3==2)?W2:W3;
    float v = W[(size_t)kin*K_DIM + col];
    wt[(size_t)chunk*8192 + col*64 + (kk ^ ((col&7)<<3))] = f2bf(v);
}

// Fused TP(fp32) -> bf16 A-tile -> MFMA mix-GEMM -> residual.
// Block = 128 rows x 128 cols of one l3's GEMM. 4 waves, each 32 rows x 128 cols
// = 2x8 tiles of 16x16 via v_mfma_f32_16x16x32_bf16.
__global__ __launch_bounds__(256) void cg_main(
    const float* __restrict__ f10, const float* __restrict__ f11,
    const float* __restrict__ f12, const float* __restrict__ f13,
    const float* __restrict__ f20, const float* __restrict__ f21,
    const float* __restrict__ f22, const float* __restrict__ f23,
    const unsigned short* __restrict__ wt,
    const float* __restrict__ C2, float* __restrict__ out)
{
    __shared__ __align__(16) unsigned char Asb[128*128]; // A: row*128 + (2k ^ ((row&7)<<4))
    __shared__ __align__(16) unsigned char Wtb[128*128]; // B: pre-swizzled, linear copy
    __shared__ float C2s[49];
    __shared__ int rowN[128];
    __shared__ int rowM[128];

    const float* f1s[4] = {f10,f11,f12,f13};
    const float* f2s[4] = {f20,f21,f22,f23};

    int b = blockIdx.x;
    int l3, rb;
    if (b < 64)       { l3=0; rb=b; }
    else if (b < 256) { l3=1; rb=b-64; }
    else if (b < 576) { l3=2; rb=b-256; }
    else              { l3=3; rb=b-576; }
    const int TL3 = 2*l3+1;
    const int row0 = rb*128;
    const int tid  = threadIdx.x;
    const size_t obase = (size_t)1048576 * (size_t)((l3==0)?0:(l3==1)?1:(l3==2)?4:9);

    if (tid < 128) {
        int rg = row0 + tid;
        rowN[tid] = rg / TL3;
        rowM[tid] = rg % TL3;
    }

    f32x4 acc[2][8];
    #pragma unroll
    for (int t=0;t<2;++t)
        #pragma unroll
        for (int c=0;c<8;++c)
            acc[t][c] = (f32x4){0.f,0.f,0.f,0.f};

    // TP mapping
    const int tx = tid & 31;   // kk-pair: kk0 = 2*tx
    const int ty = tid >> 5;   // row phase 0..7
    // MFMA mapping
    const int lane = tid & 63;
    const int wid  = tid >> 6;
    const int lr   = lane & 15;
    const int lg   = lane >> 4;

    const int np = d_np[l3];
    const int chunkbase = d_csum[l3];

    for (int pi=0; pi<np; ++pi) {
        int p  = d_pl3[l3][pi];
        int l1 = d_l1[p], l2 = d_l2[p];
        const float* __restrict__ F1 = f1s[l1];
        const float* __restrict__ F2 = f2s[l2];
        const int d1 = 2*l1+1, d2 = 2*l2+1;
        if (tid < 49) C2s[tid] = C2[p*49 + tid];

        for (int h=0; h<2; ++h) {
            __syncthreads();   // prev MFMA done (LDS reuse) + C2s/rowN visible
            // --- stage pre-swizzled W tile: 16KB linear copy ---
            {
                const float4* src = reinterpret_cast<const float4*>(
                    wt + (size_t)(chunkbase + pi*2 + h) * 8192);
                float4* dst = reinterpret_cast<float4*>(Wtb);
                #pragma unroll
                for (int it=0; it<4; ++it)
                    dst[tid + it*256] = src[tid + it*256];
            }
            // --- TP: compute 2 channels x 16 rows per thread, write bf16x2 swizzled ---
            const int ch = h*64 + 2*tx;
            #pragma unroll 2
            for (int jj=0; jj<16; ++jj) {
                int r = ty + 8*jj;
                int n = rowN[r];
                int m3 = rowM[r] - l3;
                float a0 = 0.f, a1 = 0.f;
                for (int m1i=0; m1i<d1; ++m1i) {
                    int m2i = m3 - (m1i - l1) + l2;
                    if (m2i >= 0 && m2i < d2) {
                        float c = C2s[m1i*7+m2i];
                        if (c != 0.f) {
                            const float2 v1 = *reinterpret_cast<const float2*>(
                                &F1[((size_t)n*d1+m1i)*K_DIM + ch]);
                            const float2 v2 = *reinterpret_cast<const float2*>(
                                &F2[((size_t)n*d2+m2i)*K_DIM + ch]);
                            a0 = fmaf(c*v1.x, v2.x, a0);
                            a1 = fmaf(c*v1.y, v2.y, a1);
                        }
                    }
                }
                unsigned int pack = (unsigned int)f2bf(a0) | ((unsigned int)f2bf(a1) << 16);
                *reinterpret_cast<unsigned int*>(
                    Asb + r*128 + ((4*tx) ^ ((r&7)<<4))) = pack;
            }
            __syncthreads();
            // --- MFMA: 2 K=32 steps, 2 row-tiles x 8 col-tiles ---
            #pragma unroll
            for (int ks=0; ks<2; ++ks) {
                const int kb = 16*lg + 64*ks;   // byte offset of this lane's 8 bf16 along k
                short8 af[2], bf[8];
                #pragma unroll
                for (int t=0;t<2;++t) {
                    int r = 32*wid + 16*t + lr;
                    af[t] = *reinterpret_cast<const short8*>(
                        Asb + r*128 + (kb ^ ((r&7)<<4)));
                }
                #pragma unroll
                for (int c=0;c<8;++c) {
                    int col = 16*c + lr;
                    bf[c] = *reinterpret_cast<const short8*>(
                        Wtb + col*128 + (kb ^ ((col&7)<<4)));
                }
                #pragma unroll
                for (int t=0;t<2;++t)
                    #pragma unroll
                    for (int c=0;c<8;++c)
                        acc[t][c] = __builtin_amdgcn_mfma_f32_16x16x32_bf16(
                            af[t], bf[c], acc[t][c], 0, 0, 0);
            }
        }
    }

    // --- epilogue: residual + store. D mapping: col=lane&15, row=4*(lane>>4)+i ---
    const float* __restrict__ F1r = f1s[l3];
    #pragma unroll
    for (int t=0;t<2;++t) {
        #pragma unroll
        for (int i=0;i<4;++i) {
            int r = 32*wid + 16*t + 4*lg + i;
            size_t ro = (size_t)(row0 + r) * K_DIM;
            #pragma unroll
            for (int c=0;c<8;++c) {
                int col = 16*c + lr;
                out[obase + ro + col] = F1r[ro + col] + acc[t][c][i];
            }
        }
    }
}

extern "C" void kernel_launch(void* const* d_in, const int* in_sizes, int n_in,
                              void* d_out, int out_size, void* d_ws, size_t ws_size,
                              hipStream_t stream) {
    // setup_inputs dict order is INTERLEAVED: f1_l, f2_l, W_l per l
    const float* f10 = (const float*)d_in[0];
    const float* f20 = (const float*)d_in[1];
    const float* W0  = (const float*)d_in[2];
    const float* f11 = (const float*)d_in[3];
    const float* f21 = (const float*)d_in[4];
    const float* W1  = (const float*)d_in[5];
    const float* f12 = (const float*)d_in[6];
    const float* f22 = (const float*)d_in[7];
    const float* W2  = (const float*)d_in[8];
    const float* f13 = (const float*)d_in[9];
    const float* f23 = (const float*)d_in[10];
    const float* W3  = (const float*)d_in[11];

    float* C2 = (float*)d_ws;                                      // 6664 B
    unsigned short* wtw = (unsigned short*)((char*)d_ws + 8192);   // 68*16KB = 1.09 MB
    float* out = (float*)d_out;

    hipLaunchKernelGGL(cg_init, dim3(7), dim3(256), 0, stream, C2);
    hipLaunchKernelGGL(wt_prep, dim3(68*32), dim3(256), 0, stream, W0, W1, W2, W3, wtw);
    hipLaunchKernelGGL(cg_main, dim3(1024), dim3(256), 0, stream,
        f10,f11,f12,f13, f20,f21,f22,f23, wtw, C2, out);
}

// Round 4
// 312.178 us; speedup vs baseline: 6.1409x; 3.4311x over previous
//
#include <hip/hip_runtime.h>

#define K_DIM 128

typedef __attribute__((ext_vector_type(8))) short short8;
typedef __attribute__((ext_vector_type(4))) float f32x4;

// ---- compile-time path tables: PATHS order = l1-major, l2, l3 ascending ----
constexpr int C_L1[34] = {0,0,0,0, 1,1,1,1,1,1,1,1,1, 2,2,2,2,2,2,2,2,2,2,2, 3,3,3,3,3,3,3,3,3,3};
constexpr int C_L2[34] = {0,1,2,3, 0,1,1,1,2,2,2,3,3, 0,1,1,1,2,2,2,2,3,3,3, 0,1,1,2,2,2,3,3,3,3};
constexpr int C_L3[34] = {0,1,2,3, 1,0,1,2,1,2,3,2,3, 2,1,2,3,0,1,2,3,1,2,3, 3,2,3,1,2,3,0,1,2,3};
constexpr int C_NP[4]  = {4,9,11,10};
constexpr int C_PL[4][11] = {
  {0,5,17,30, 0,0,0,0,0,0,0},
  {1,4,6,8,14,18,21,27,31, 0,0},
  {2,7,9,11,13,15,19,22,25,28,32},
  {3,10,12,16,20,23,24,26,29,33, 0}
};
constexpr int C_CSUM[4] = {0,8,26,48};      // 64-ch chunk base per l3
constexpr size_t FOFF[4] = {0, 1048576, 4194304, 9437184};  // per-l elem offsets (N*(2l+1)*128)
constexpr int FSZ[4] = {1048576, 3145728, 5242880, 7340032};
constexpr size_t FTOT = 16777216;           // elems per f-set

__device__ double dfactd(int n){ double r=1.0; for(int i=2;i<=n;++i) r*=(double)i; return r; }

__device__ __forceinline__ unsigned short f2bf(float x) {
    unsigned int b = __float_as_uint(x);
    return (unsigned short)((b + 0x7FFFu + ((b >> 16) & 1u)) >> 16);
}

// C2[p][m1i][m2i], 34*49 floats at d_ws+0
__global__ void cg_init(float* __restrict__ C2) {
    int e = blockIdx.x*blockDim.x + threadIdx.x;
    if (e >= 34*49) return;
    int p = e/49, r = e%49, m1i = r/7, m2i = r%7;
    int l1 = C_L1[p], l2 = C_L2[p], l3 = C_L3[p];
    float val = 0.f;
    if (m1i < 2*l1+1 && m2i < 2*l2+1) {
        int m1 = m1i-l1, m2 = m2i-l2, m3 = m1+m2;
        if (m3 >= -l3 && m3 <= l3) {
            double pref = sqrt((double)(2*l3+1) * dfactd(l3+l1-l2)*dfactd(l3-l1+l2)
                               * dfactd(l1+l2-l3) / dfactd(l1+l2+l3+1));
            pref *= sqrt(dfactd(l3+m3)*dfactd(l3-m3)*dfactd(l1-m1)*dfactd(l1+m1)
                         *dfactd(l2-m2)*dfactd(l2+m2));
            int kmin = max(0, max(l2-l3-m1, l1-l3+m2));
            int kmax = min(l1+l2-l3, min(l1-m1, l2+m2));
            double s = 0.0;
            for (int k=kmin;k<=kmax;++k) {
                double t = dfactd(k)*dfactd(l1+l2-l3-k)*dfactd(l1-m1-k)
                         * dfactd(l2+m2-k)*dfactd(l3-l2+m1+k)*dfactd(l3-l1-m2+k);
                s += ((k&1)? -1.0:1.0)/t;
            }
            val = (float)(pref*s);
        }
    }
    C2[e] = val;
}

// W -> bf16 transposed+swizzled tiles (same layout as round 3)
__global__ void wt_prep(const float* __restrict__ W0, const float* __restrict__ W1,
                        const float* __restrict__ W2, const float* __restrict__ W3,
                        unsigned short* __restrict__ wt) {
    int b = blockIdx.x;
    int chunk = b >> 5;
    int e = ((b & 31) << 8) + threadIdx.x;
    int kk = e & 63, col = e >> 6;
    int l3 = (chunk < 8) ? 0 : (chunk < 26) ? 1 : (chunk < 48) ? 2 : 3;
    int local = chunk - C_CSUM[l3];
    int kin = local*64 + kk;
    const float* W = (l3==0)?W0:(l3==1)?W1:(l3==2)?W2:W3;
    float v = W[(size_t)kin*K_DIM + col];
    wt[(size_t)chunk*8192 + col*64 + (kk ^ ((col&7)<<3))] = f2bf(v);
}

// f1/f2 -> bf16 packed copies in ws. grid: (x up to 7168, y=0..7)
__global__ void fpack(const float* __restrict__ s0, const float* __restrict__ s1,
                      const float* __restrict__ s2, const float* __restrict__ s3,
                      const float* __restrict__ s4, const float* __restrict__ s5,
                      const float* __restrict__ s6, const float* __restrict__ s7,
                      unsigned short* __restrict__ dst) {
    int y = blockIdx.y;              // 0..3: f1 l; 4..7: f2 l
    int l = y & 3, fi = y >> 2;
    const float* srcs[8] = {s0,s1,s2,s3,s4,s5,s6,s7};
    const float* src = srcs[y];
    int i4 = blockIdx.x*256 + threadIdx.x;
    if (i4*4 >= FSZ[l]) return;
    float4 v = reinterpret_cast<const float4*>(src)[i4];
    unsigned int u0 = (unsigned int)f2bf(v.x) | ((unsigned int)f2bf(v.y) << 16);
    unsigned int u1 = (unsigned int)f2bf(v.z) | ((unsigned int)f2bf(v.w) << 16);
    unsigned short* d = dst + fi*FTOT + FOFF[l] + (size_t)i4*4;
    *reinterpret_cast<uint2*>(d) = make_uint2(u0, u1);
}

#define DO_DW(i, u, v) { \
    float x0 = __uint_as_float((u)<<16); \
    float x1 = __uint_as_float((u)&0xFFFF0000u); \
    float y0 = __uint_as_float((v)<<16); \
    float y1 = __uint_as_float((v)&0xFFFF0000u); \
    a[2*(i)]   = fmaf(c*x0, y0, a[2*(i)]); \
    a[2*(i)+1] = fmaf(c*x1, y1, a[2*(i)+1]); }

#define DO_F4(i, p, q) { \
    a[4*(i)+0] = fmaf(c*(p).x, (q).x, a[4*(i)+0]); \
    a[4*(i)+1] = fmaf(c*(p).y, (q).y, a[4*(i)+1]); \
    a[4*(i)+2] = fmaf(c*(p).z, (q).z, a[4*(i)+2]); \
    a[4*(i)+3] = fmaf(c*(p).w, (q).w, a[4*(i)+3]); }

// One (path, h) pair: TP -> swizzled A tile, W stage, MFMA accumulate.
template<int L3, bool PK, int PI>
__device__ __forceinline__ void chunk_pair(
    const float* const (&f1p)[4], const float* const (&f2p)[4],
    const unsigned short* __restrict__ f1b, const unsigned short* __restrict__ f2b,
    const unsigned short* __restrict__ wt, const float* __restrict__ C2,
    float* C2s, unsigned char* Asb, unsigned char* Wtb,
    int tid, int n, int m3, int r, int chq,
    int wid, int lr, int lg, f32x4 (&acc)[8])
{
    constexpr int P  = C_PL[L3][PI];
    constexpr int l1 = C_L1[P], l2 = C_L2[P];
    constexpr int d1 = 2*l1+1, d2 = 2*l2+1;

    if (tid < 49) C2s[tid] = C2[P*49 + tid];

    for (int h = 0; h < 2; ++h) {
        __syncthreads();   // prev MFMA done; C2s visible
        // ---- TP: 1 row x 16 ch per thread, fully unrolled terms ----
        float a[16];
        #pragma unroll
        for (int j=0;j<16;++j) a[j] = 0.f;

        if constexpr (PK) {
            const unsigned short* bp1 = f1b + FOFF[l1] + (size_t)n*(d1*128) + h*64 + chq;
            const unsigned short* bp2 = f2b + FOFF[l2] + (size_t)n*(d2*128) + h*64 + chq;
            #pragma unroll
            for (int m1i=0; m1i<d1; ++m1i) {
                int m2i = m3 + (l1 + l2 - m1i);
                if (m2i >= 0 && m2i < d2) {
                    float c = C2s[m1i*7 + m2i];
                    uint4 qa = *reinterpret_cast<const uint4*>(bp1 + m1i*128);
                    uint4 qb = *reinterpret_cast<const uint4*>(bp1 + m1i*128 + 8);
                    uint4 ra = *reinterpret_cast<const uint4*>(bp2 + m2i*128);
                    uint4 rb = *reinterpret_cast<const uint4*>(bp2 + m2i*128 + 8);
                    DO_DW(0, qa.x, ra.x)  DO_DW(1, qa.y, ra.y)
                    DO_DW(2, qa.z, ra.z)  DO_DW(3, qa.w, ra.w)
                    DO_DW(4, qb.x, rb.x)  DO_DW(5, qb.y, rb.y)
                    DO_DW(6, qb.z, rb.z)  DO_DW(7, qb.w, rb.w)
                }
            }
        } else {
            const float* bp1 = f1p[l1] + (size_t)n*(d1*128) + h*64 + chq;
            const float* bp2 = f2p[l2] + (size_t)n*(d2*128) + h*64 + chq;
            #pragma unroll
            for (int m1i=0; m1i<d1; ++m1i) {
                int m2i = m3 + (l1 + l2 - m1i);
                if (m2i >= 0 && m2i < d2) {
                    float c = C2s[m1i*7 + m2i];
                    float4 p0 = *reinterpret_cast<const float4*>(bp1 + m1i*128);
                    float4 p1 = *reinterpret_cast<const float4*>(bp1 + m1i*128 + 4);
                    float4 p2 = *reinterpret_cast<const float4*>(bp1 + m1i*128 + 8);
                    float4 p3 = *reinterpret_cast<const float4*>(bp1 + m1i*128 + 12);
                    float4 q0 = *reinterpret_cast<const float4*>(bp2 + m2i*128);
                    float4 q1 = *reinterpret_cast<const float4*>(bp2 + m2i*128 + 4);
                    float4 q2 = *reinterpret_cast<const float4*>(bp2 + m2i*128 + 8);
                    float4 q3 = *reinterpret_cast<const float4*>(bp2 + m2i*128 + 12);
                    DO_F4(0, p0, q0)  DO_F4(1, p1, q1)
                    DO_F4(2, p2, q2)  DO_F4(3, p3, q3)
                }
            }
        }
        // pack to bf16 + swizzled LDS write (2 x b128)
        unsigned int pk[8];
        #pragma unroll
        for (int j=0;j<8;++j)
            pk[j] = (unsigned int)f2bf(a[2*j]) | ((unsigned int)f2bf(a[2*j+1]) << 16);
        {
            int ab = r*128, g0 = chq*2, key = (r&7)<<4;
            *reinterpret_cast<uint4*>(Asb + ab + ( g0        ^ key)) = make_uint4(pk[0],pk[1],pk[2],pk[3]);
            *reinterpret_cast<uint4*>(Asb + ab + ((g0 + 16)  ^ key)) = make_uint4(pk[4],pk[5],pk[6],pk[7]);
        }
        // ---- stage pre-swizzled W tile (16KB), after TP so loads overlap ----
        {
            const float4* src = reinterpret_cast<const float4*>(
                wt + (size_t)(C_CSUM[L3] + PI*2 + h) * 8192);
            float4* dst = reinterpret_cast<float4*>(Wtb);
            dst[tid]       = src[tid];
            dst[tid + 512] = src[tid + 512];
        }
        __syncthreads();
        // ---- MFMA: 2 K=32 steps, 1 row-tile x 8 col-tiles per wave ----
        #pragma unroll
        for (int ks=0; ks<2; ++ks) {
            const int kb = 16*lg + 64*ks;
            const int arow = 16*wid + lr;
            short8 af = *reinterpret_cast<const short8*>(
                Asb + arow*128 + (kb ^ ((arow&7)<<4)));
            #pragma unroll
            for (int cc=0; cc<8; ++cc) {
                int col = 16*cc + lr;
                short8 bf = *reinterpret_cast<const short8*>(
                    Wtb + col*128 + (kb ^ ((col&7)<<4)));
                acc[cc] = __builtin_amdgcn_mfma_f32_16x16x32_bf16(af, bf, acc[cc], 0, 0, 0);
            }
        }
    }
}

template<int L3, bool PK, int PI>
__device__ __forceinline__ void paths_from(
    const float* const (&f1p)[4], const float* const (&f2p)[4],
    const unsigned short* __restrict__ f1b, const unsigned short* __restrict__ f2b,
    const unsigned short* __restrict__ wt, const float* __restrict__ C2,
    float* C2s, unsigned char* Asb, unsigned char* Wtb,
    int tid, int n, int m3, int r, int chq,
    int wid, int lr, int lg, f32x4 (&acc)[8])
{
    if constexpr (PI < C_NP[L3]) {
        chunk_pair<L3, PK, PI>(f1p, f2p, f1b, f2b, wt, C2, C2s, Asb, Wtb,
                               tid, n, m3, r, chq, wid, lr, lg, acc);
        paths_from<L3, PK, PI+1>(f1p, f2p, f1b, f2b, wt, C2, C2s, Asb, Wtb,
                                 tid, n, m3, r, chq, wid, lr, lg, acc);
    }
}

template<int L3, bool PK>
__device__ __forceinline__ void run_l3(
    int rb,
    const float* const (&f1p)[4], const float* const (&f2p)[4],
    const unsigned short* __restrict__ f1b, const unsigned short* __restrict__ f2b,
    const unsigned short* __restrict__ wt, const float* __restrict__ C2,
    float* __restrict__ out,
    float* C2s, unsigned char* Asb, unsigned char* Wtb)
{
    constexpr int TL3 = 2*L3+1;
    const int tid = threadIdx.x;
    const int row0 = rb*128;
    const int r   = tid >> 2;          // TP row 0..127
    const int chq = (tid & 3) * 16;    // TP ch base within 64-half
    const int gr  = row0 + r;
    const int n   = gr / TL3;          // constexpr divisor -> magic mul
    const int m3  = (gr - n*TL3) - L3;
    const int lane = tid & 63, wid = tid >> 6;
    const int lr = lane & 15, lg = lane >> 4;
    constexpr size_t OB = FOFF[L3];

    f32x4 acc[8];
    #pragma unroll
    for (int c=0;c<8;++c) acc[c] = (f32x4){0.f,0.f,0.f,0.f};

    paths_from<L3, PK, 0>(f1p, f2p, f1b, f2b, wt, C2, C2s, Asb, Wtb,
                          tid, n, m3, r, chq, wid, lr, lg, acc);

    // epilogue: residual + store. D: col=lane&15, row=4*(lane>>4)+i
    const float* __restrict__ F1r = f1p[L3];
    #pragma unroll
    for (int i=0;i<4;++i) {
        int rr = 16*wid + 4*lg + i;
        size_t ro = (size_t)(row0 + rr) * K_DIM;
        #pragma unroll
        for (int cc=0;cc<8;++cc) {
            int col = 16*cc + lr;
            out[OB + ro + col] = F1r[ro + col] + acc[cc][i];
        }
    }
}

template<bool PK>
__global__ __launch_bounds__(512, 4) void cg_main(
    const float* __restrict__ f10, const float* __restrict__ f11,
    const float* __restrict__ f12, const float* __restrict__ f13,
    const float* __restrict__ f20, const float* __restrict__ f21,
    const float* __restrict__ f22, const float* __restrict__ f23,
    const unsigned short* __restrict__ f1b, const unsigned short* __restrict__ f2b,
    const unsigned short* __restrict__ wt,
    const float* __restrict__ C2, float* __restrict__ out)
{
    __shared__ __align__(16) unsigned char Asb[128*128];
    __shared__ __align__(16) unsigned char Wtb[128*128];
    __shared__ float C2s[49];

    const float* const f1p[4] = {f10,f11,f12,f13};
    const float* const f2p[4] = {f20,f21,f22,f23};

    int b = blockIdx.x;
    if (b < 64)
        run_l3<0,PK>(b,     f1p, f2p, f1b, f2b, wt, C2, out, C2s, Asb, Wtb);
    else if (b < 256)
        run_l3<1,PK>(b-64,  f1p, f2p, f1b, f2b, wt, C2, out, C2s, Asb, Wtb);
    else if (b < 576)
        run_l3<2,PK>(b-256, f1p, f2p, f1b, f2b, wt, C2, out, C2s, Asb, Wtb);
    else
        run_l3<3,PK>(b-576, f1p, f2p, f1b, f2b, wt, C2, out, C2s, Asb, Wtb);
}

extern "C" void kernel_launch(void* const* d_in, const int* in_sizes, int n_in,
                              void* d_out, int out_size, void* d_ws, size_t ws_size,
                              hipStream_t stream) {
    const float* f10 = (const float*)d_in[0];
    const float* f20 = (const float*)d_in[1];
    const float* W0  = (const float*)d_in[2];
    const float* f11 = (const float*)d_in[3];
    const float* f21 = (const float*)d_in[4];
    const float* W1  = (const float*)d_in[5];
    const float* f12 = (const float*)d_in[6];
    const float* f22 = (const float*)d_in[7];
    const float* W2  = (const float*)d_in[8];
    const float* f13 = (const float*)d_in[9];
    const float* f23 = (const float*)d_in[10];
    const float* W3  = (const float*)d_in[11];

    float* C2 = (float*)d_ws;                                       // 6664 B
    unsigned short* wtw = (unsigned short*)((char*)d_ws + 8192);    // 1.09 MB
    unsigned short* f1b = (unsigned short*)((char*)d_ws + 1122304); // 32 MB
    unsigned short* f2b = f1b + FTOT;                               // 32 MB
    float* out = (float*)d_out;
    const size_t NEED = 1122304 + 2*FTOT*sizeof(unsigned short);

    hipLaunchKernelGGL(cg_init, dim3(7), dim3(256), 0, stream, C2);
    hipLaunchKernelGGL(wt_prep, dim3(68*32), dim3(256), 0, stream, W0, W1, W2, W3, wtw);
    if (ws_size >= NEED) {
        hipLaunchKernelGGL(fpack, dim3(7168, 8), dim3(256), 0, stream,
            f10, f11, f12, f13, f20, f21, f22, f23, f1b);
        hipLaunchKernelGGL(cg_main<true>, dim3(1024), dim3(512), 0, stream,
            f10,f11,f12,f13, f20,f21,f22,f23, f1b, f2b, wtw, C2, out);
    } else {
        hipLaunchKernelGGL(cg_main<false>, dim3(1024), dim3(512), 0, stream,
            f10,f11,f12,f13, f20,f21,f22,f23, f1b, f2b, wtw, C2, out);
    }
}

// Round 5
// 272.560 us; speedup vs baseline: 7.0335x; 1.1454x over previous
//
#include <hip/hip_runtime.h>

#define K_DIM 128

typedef __attribute__((ext_vector_type(8))) short short8;
typedef __attribute__((ext_vector_type(4))) float f32x4;

// ---- compile-time path tables: PATHS order = l1-major, l2, l3 ascending ----
constexpr int C_L1[34] = {0,0,0,0, 1,1,1,1,1,1,1,1,1, 2,2,2,2,2,2,2,2,2,2,2, 3,3,3,3,3,3,3,3,3,3};
constexpr int C_L2[34] = {0,1,2,3, 0,1,1,1,2,2,2,3,3, 0,1,1,1,2,2,2,2,3,3,3, 0,1,1,2,2,2,3,3,3,3};
constexpr int C_L3[34] = {0,1,2,3, 1,0,1,2,1,2,3,2,3, 2,1,2,3,0,1,2,3,1,2,3, 3,2,3,1,2,3,0,1,2,3};
constexpr int C_NP[4]  = {4,9,11,10};
constexpr int C_PL[4][11] = {
  {0,5,17,30, 0,0,0,0,0,0,0},
  {1,4,6,8,14,18,21,27,31, 0,0},
  {2,7,9,11,13,15,19,22,25,28,32},
  {3,10,12,16,20,23,24,26,29,33, 0}
};
constexpr int C_CSUM[4] = {0,8,26,48};      // 64-ch chunk base per l3
constexpr size_t FOFF[4] = {0, 1048576, 4194304, 9437184};  // per-l elem offsets
constexpr int FSZ[4] = {1048576, 3145728, 5242880, 7340032};
constexpr size_t FTOT = 16777216;           // elems per f-set

__device__ double dfactd(int n){ double r=1.0; for(int i=2;i<=n;++i) r*=(double)i; return r; }

__device__ __forceinline__ unsigned short f2bf(float x) {
    unsigned int b = __float_as_uint(x);
    return (unsigned short)((b + 0x7FFFu + ((b >> 16) & 1u)) >> 16);
}

// packed RNE f32x2 -> bf16x2 (single VALU inst; pure-ALU asm, no mem hazard)
__device__ __forceinline__ unsigned int cvtpk(float lo, float hi) {
    unsigned int r;
    asm("v_cvt_pk_bf16_f32 %0, %1, %2" : "=v"(r) : "v"(lo), "v"(hi));
    return r;
}

// C2[p][m1i][m2i], 34*49 floats at d_ws+0
__global__ void cg_init(float* __restrict__ C2) {
    int e = blockIdx.x*blockDim.x + threadIdx.x;
    if (e >= 34*49) return;
    int p = e/49, r = e%49, m1i = r/7, m2i = r%7;
    int l1 = C_L1[p], l2 = C_L2[p], l3 = C_L3[p];
    float val = 0.f;
    if (m1i < 2*l1+1 && m2i < 2*l2+1) {
        int m1 = m1i-l1, m2 = m2i-l2, m3 = m1+m2;
        if (m3 >= -l3 && m3 <= l3) {
            double pref = sqrt((double)(2*l3+1) * dfactd(l3+l1-l2)*dfactd(l3-l1+l2)
                               * dfactd(l1+l2-l3) / dfactd(l1+l2+l3+1));
            pref *= sqrt(dfactd(l3+m3)*dfactd(l3-m3)*dfactd(l1-m1)*dfactd(l1+m1)
                         *dfactd(l2-m2)*dfactd(l2+m2));
            int kmin = max(0, max(l2-l3-m1, l1-l3+m2));
            int kmax = min(l1+l2-l3, min(l1-m1, l2+m2));
            double s = 0.0;
            for (int k=kmin;k<=kmax;++k) {
                double t = dfactd(k)*dfactd(l1+l2-l3-k)*dfactd(l1-m1-k)
                         * dfactd(l2+m2-k)*dfactd(l3-l2+m1+k)*dfactd(l3-l1-m2+k);
                s += ((k&1)? -1.0:1.0)/t;
            }
            val = (float)(pref*s);
        }
    }
    C2[e] = val;
}

// W -> bf16 transposed+swizzled tiles
__global__ void wt_prep(const float* __restrict__ W0, const float* __restrict__ W1,
                        const float* __restrict__ W2, const float* __restrict__ W3,
                        unsigned short* __restrict__ wt) {
    int b = blockIdx.x;
    int chunk = b >> 5;
    int e = ((b & 31) << 8) + threadIdx.x;
    int kk = e & 63, col = e >> 6;
    int l3 = (chunk < 8) ? 0 : (chunk < 26) ? 1 : (chunk < 48) ? 2 : 3;
    int local = chunk - C_CSUM[l3];
    int kin = local*64 + kk;
    const float* W = (l3==0)?W0:(l3==1)?W1:(l3==2)?W2:W3;
    float v = W[(size_t)kin*K_DIM + col];
    wt[(size_t)chunk*8192 + col*64 + (kk ^ ((col&7)<<3))] = f2bf(v);
}

// f1/f2 -> bf16 packed copies in ws
__global__ void fpack(const float* __restrict__ s0, const float* __restrict__ s1,
                      const float* __restrict__ s2, const float* __restrict__ s3,
                      const float* __restrict__ s4, const float* __restrict__ s5,
                      const float* __restrict__ s6, const float* __restrict__ s7,
                      unsigned short* __restrict__ dst) {
    int y = blockIdx.y;
    int l = y & 3, fi = y >> 2;
    const float* srcs[8] = {s0,s1,s2,s3,s4,s5,s6,s7};
    const float* src = srcs[y];
    int i4 = blockIdx.x*256 + threadIdx.x;
    if (i4*4 >= FSZ[l]) return;
    float4 v = reinterpret_cast<const float4*>(src)[i4];
    unsigned int u0 = (unsigned int)f2bf(v.x) | ((unsigned int)f2bf(v.y) << 16);
    unsigned int u1 = (unsigned int)f2bf(v.z) | ((unsigned int)f2bf(v.w) << 16);
    unsigned short* d = dst + fi*FTOT + FOFF[l] + (size_t)i4*4;
    *reinterpret_cast<uint2*>(d) = make_uint2(u0, u1);
}

#define DO_DW(i, u, v) { \
    float x0 = __uint_as_float((u)<<16); \
    float x1 = __uint_as_float((u)&0xFFFF0000u); \
    float y0 = __uint_as_float((v)<<16); \
    float y1 = __uint_as_float((v)&0xFFFF0000u); \
    a[2*(i)]   = fmaf(c*x0, y0, a[2*(i)]); \
    a[2*(i)+1] = fmaf(c*x1, y1, a[2*(i)+1]); }

// One (path, h) pair: W-load hoist, TP -> swizzled A tile, MFMA accumulate.
template<int L3, int PI>
__device__ __forceinline__ void chunk_pair(
    const unsigned short* __restrict__ f1b, const unsigned short* __restrict__ f2b,
    const unsigned short* __restrict__ wt, const float* __restrict__ C2,
    float* C2s, unsigned char* Asb, unsigned char* Wtb,
    int tid, int n, int m3, int r, int chq,
    int wid, int lr, int lg, f32x4 (&acc)[8])
{
    constexpr int P  = C_PL[L3][PI];
    constexpr int l1 = C_L1[P], l2 = C_L2[P];
    constexpr int d1 = 2*l1+1, d2 = 2*l2+1;

    if (tid < 49) C2s[tid] = C2[P*49 + tid];

    #pragma unroll
    for (int h = 0; h < 2; ++h) {
        __syncthreads();   // prev MFMA done; C2s visible
        // ---- issue W-tile global loads early (in flight during TP) ----
        const float4* wsrc = reinterpret_cast<const float4*>(
            wt + (size_t)(C_CSUM[L3] + PI*2 + h) * 8192);
        float4 w0 = wsrc[tid];
        float4 w1 = wsrc[tid + 512];
        // ---- TP: 1 row x 16 ch per thread, fully unrolled terms ----
        float a[16];
        #pragma unroll
        for (int j=0;j<16;++j) a[j] = 0.f;
        {
            const unsigned short* bp1 = f1b + FOFF[l1] + (size_t)n*(d1*128) + h*64 + chq;
            const unsigned short* bp2 = f2b + FOFF[l2] + (size_t)n*(d2*128) + h*64 + chq;
            #pragma unroll
            for (int m1i=0; m1i<d1; ++m1i) {
                int m2i = m3 + (l1 + l2 - m1i);
                if (m2i >= 0 && m2i < d2) {
                    float c = C2s[m1i*7 + m2i];
                    uint4 qa = *reinterpret_cast<const uint4*>(bp1 + m1i*128);
                    uint4 qb = *reinterpret_cast<const uint4*>(bp1 + m1i*128 + 8);
                    uint4 ra = *reinterpret_cast<const uint4*>(bp2 + m2i*128);
                    uint4 rb = *reinterpret_cast<const uint4*>(bp2 + m2i*128 + 8);
                    DO_DW(0, qa.x, ra.x)  DO_DW(1, qa.y, ra.y)
                    DO_DW(2, qa.z, ra.z)  DO_DW(3, qa.w, ra.w)
                    DO_DW(4, qb.x, rb.x)  DO_DW(5, qb.y, rb.y)
                    DO_DW(6, qb.z, rb.z)  DO_DW(7, qb.w, rb.w)
                }
            }
        }
        // pack to bf16 (v_cvt_pk) + swizzled LDS write (2 x b128)
        unsigned int pk[8];
        #pragma unroll
        for (int j=0;j<8;++j) pk[j] = cvtpk(a[2*j], a[2*j+1]);
        {
            int ab = r*128, g0 = chq*2, key = (r&7)<<4;
            *reinterpret_cast<uint4*>(Asb + ab + ( g0        ^ key)) = make_uint4(pk[0],pk[1],pk[2],pk[3]);
            *reinterpret_cast<uint4*>(Asb + ab + ((g0 + 16)  ^ key)) = make_uint4(pk[4],pk[5],pk[6],pk[7]);
        }
        // ---- W LDS write (loads issued above have had TP to land) ----
        {
            float4* dst = reinterpret_cast<float4*>(Wtb);
            dst[tid]       = w0;
            dst[tid + 512] = w1;
        }
        __syncthreads();
        // ---- MFMA: 2 K=32 steps, 1 row-tile x 8 col-tiles per wave ----
        #pragma unroll
        for (int ks=0; ks<2; ++ks) {
            const int kb = 16*lg + 64*ks;
            const int arow = 16*wid + lr;
            short8 af = *reinterpret_cast<const short8*>(
                Asb + arow*128 + (kb ^ ((arow&7)<<4)));
            #pragma unroll
            for (int cc=0; cc<8; ++cc) {
                int col = 16*cc + lr;
                short8 bf = *reinterpret_cast<const short8*>(
                    Wtb + col*128 + (kb ^ ((col&7)<<4)));
                acc[cc] = __builtin_amdgcn_mfma_f32_16x16x32_bf16(af, bf, acc[cc], 0, 0, 0);
            }
        }
    }
}

template<int L3, int PI>
__device__ __forceinline__ void paths_from(
    const unsigned short* __restrict__ f1b, const unsigned short* __restrict__ f2b,
    const unsigned short* __restrict__ wt, const float* __restrict__ C2,
    float* C2s, unsigned char* Asb, unsigned char* Wtb,
    int tid, int n, int m3, int r, int chq,
    int wid, int lr, int lg, f32x4 (&acc)[8])
{
    if constexpr (PI < C_NP[L3]) {
        chunk_pair<L3, PI>(f1b, f2b, wt, C2, C2s, Asb, Wtb,
                           tid, n, m3, r, chq, wid, lr, lg, acc);
        paths_from<L3, PI+1>(f1b, f2b, wt, C2, C2s, Asb, Wtb,
                             tid, n, m3, r, chq, wid, lr, lg, acc);
    }
}

template<int L3>
__device__ __forceinline__ void run_l3(
    int rb, const float* __restrict__ f1res,
    const unsigned short* __restrict__ f1b, const unsigned short* __restrict__ f2b,
    const unsigned short* __restrict__ wt, const float* __restrict__ C2,
    float* __restrict__ out,
    float* C2s, unsigned char* Asb, unsigned char* Wtb)
{
    constexpr int TL3 = 2*L3+1;
    const int tid = threadIdx.x;
    const int row0 = rb*128;
    const int r   = tid >> 2;          // TP row 0..127
    const int chq = (tid & 3) * 16;    // TP ch base within 64-half
    const int gr  = row0 + r;
    const int n   = gr / TL3;
    const int m3  = (gr - n*TL3) - L3;
    const int lane = tid & 63, wid = tid >> 6;
    const int lr = lane & 15, lg = lane >> 4;
    constexpr size_t OB = FOFF[L3];

    f32x4 acc[8];
    #pragma unroll
    for (int c=0;c<8;++c) acc[c] = (f32x4){0.f,0.f,0.f,0.f};

    paths_from<L3, 0>(f1b, f2b, wt, C2, C2s, Asb, Wtb,
                      tid, n, m3, r, chq, wid, lr, lg, acc);

    // epilogue: residual + store. D: col=lane&15, row=4*(lane>>4)+i
    #pragma unroll
    for (int i=0;i<4;++i) {
        int rr = 16*wid + 4*lg + i;
        size_t ro = (size_t)(row0 + rr) * K_DIM;
        #pragma unroll
        for (int cc=0;cc<8;++cc) {
            int col = 16*cc + lr;
            out[OB + ro + col] = f1res[ro + col] + acc[cc][i];
        }
    }
}

__global__ __launch_bounds__(512, 4) void cg_main(
    const float* __restrict__ f10, const float* __restrict__ f11,
    const float* __restrict__ f12, const float* __restrict__ f13,
    const unsigned short* __restrict__ f1b, const unsigned short* __restrict__ f2b,
    const unsigned short* __restrict__ wt,
    const float* __restrict__ C2, float* __restrict__ out)
{
    __shared__ __align__(16) unsigned char Asb[128*128];
    __shared__ __align__(16) unsigned char Wtb[128*128];
    __shared__ float C2s[49];

    // XCD-aware remap: bid%8 = XCD (round-robin). Give each XCD the blocks of
    // ALL l3 groups covering the same node slice n in [1024x, 1024(x+1)).
    int bid = blockIdx.x;
    int x = bid & 7, j = bid >> 3;
    if (j < 8)
        run_l3<0>(x*8  + j,      f10, f1b, f2b, wt, C2, out, C2s, Asb, Wtb);
    else if (j < 32)
        run_l3<1>(x*24 + (j-8),  f11, f1b, f2b, wt, C2, out, C2s, Asb, Wtb);
    else if (j < 72)
        run_l3<2>(x*40 + (j-32), f12, f1b, f2b, wt, C2, out, C2s, Asb, Wtb);
    else
        run_l3<3>(x*56 + (j-72), f13, f1b, f2b, wt, C2, out, C2s, Asb, Wtb);
}

extern "C" void kernel_launch(void* const* d_in, const int* in_sizes, int n_in,
                              void* d_out, int out_size, void* d_ws, size_t ws_size,
                              hipStream_t stream) {
    const float* f10 = (const float*)d_in[0];
    const float* f20 = (const float*)d_in[1];
    const float* W0  = (const float*)d_in[2];
    const float* f11 = (const float*)d_in[3];
    const float* f21 = (const float*)d_in[4];
    const float* W1  = (const float*)d_in[5];
    const float* f12 = (const float*)d_in[6];
    const float* f22 = (const float*)d_in[7];
    const float* W2  = (const float*)d_in[8];
    const float* f13 = (const float*)d_in[9];
    const float* f23 = (const float*)d_in[10];
    const float* W3  = (const float*)d_in[11];

    float* C2 = (float*)d_ws;                                       // 6664 B
    unsigned short* wtw = (unsigned short*)((char*)d_ws + 8192);    // 1.09 MB
    unsigned short* f1b = (unsigned short*)((char*)d_ws + 1122304); // 32 MB
    unsigned short* f2b = f1b + FTOT;                               // 32 MB
    float* out = (float*)d_out;

    hipLaunchKernelGGL(cg_init, dim3(7), dim3(256), 0, stream, C2);
    hipLaunchKernelGGL(wt_prep, dim3(68*32), dim3(256), 0, stream, W0, W1, W2, W3, wtw);
    hipLaunchKernelGGL(fpack, dim3(7168, 8), dim3(256), 0, stream,
        f10, f11, f12, f13, f20, f21, f22, f23, f1b);
    hipLaunchKernelGGL(cg_main, dim3(1024), dim3(512), 0, stream,
        f10, f11, f12, f13, f1b, f2b, wtw, C2, out);
}